// Round 15
// baseline (832.756 us; speedup 1.0000x reference)
//
#include <hip/hip_runtime.h>
#include <hip/hip_bf16.h>
#include <math.h>

typedef __bf16 bf16;
typedef __bf16 bf16x2 __attribute__((ext_vector_type(2)));
typedef __bf16 bf16x4 __attribute__((ext_vector_type(4)));
typedef __bf16 bf16x8 __attribute__((ext_vector_type(8)));
typedef float f32x4 __attribute__((ext_vector_type(4)));
typedef unsigned int u32;
typedef u32 u32x4 __attribute__((ext_vector_type(4)));

#define B_ 4
#define T_ 8192
#define D_ 512
#define H_ 16
#define HD_ 32
#define M_ (B_ * T_)  // 32768 rows
#define QKVS 1536     // fused qkv row stride

#if __has_builtin(__builtin_amdgcn_exp2f)
#define EXP2(x) __builtin_amdgcn_exp2f(x)
#else
#define EXP2(x) exp2f(x)
#endif

// address-space casts for global_load_lds
#define LDSP(p) ((__attribute__((address_space(3))) void*)(p))
#define GLBP(p) ((const __attribute__((address_space(1))) void*)(p))

// pack two f32 -> dword of 2 bf16
static __device__ __forceinline__ u32 pkbf16(float a, float b) {
  bf16x2 t;
  t[0] = (bf16)a;
  t[1] = (bf16)b;
  return __builtin_bit_cast(u32, t);
}

// v_permlane32_swap_b32: a' = [a.lo32, b.lo32], b' = [a.hi32, b.hi32]
static __device__ __forceinline__ void swap32(u32& a, u32& b) {
#if __has_builtin(__builtin_amdgcn_permlane32_swap)
  auto r = __builtin_amdgcn_permlane32_swap(a, b, false, false);
  a = r[0];
  b = r[1];
#else
  asm volatile("v_permlane32_swap_b32 %0, %1" : "+v"(a), "+v"(b));
#endif
}

// ---------------- fp32 -> bf16 convert (vectorized, grid-stride) ----------------
__global__ void k_cvt(const float* __restrict__ in, bf16* __restrict__ out, int n4) {
  int i = blockIdx.x * blockDim.x + threadIdx.x;
  const int stride = gridDim.x * blockDim.x;
  for (; i < n4; i += stride) {
    const float4 v = ((const float4*)in)[i];
    bf16x4 o;
    o.x = (bf16)v.x; o.y = (bf16)v.y; o.z = (bf16)v.z; o.w = (bf16)v.w;
    ((bf16x4*)out)[i] = o;
  }
}

// ---------------- fused Wq/Wk/Wv transpose+convert -> wqkvT[1536][512] ----------------
// rows 0-511 = Wq^T (pre-scaled by scale*log2e), 512-1023 = Wk^T, 1024-1535 = Wv^T.
// Wave-uniform matrix select (n constant across each 64-lane wave).
__global__ void k_cvt_T3(const float* __restrict__ Wq, const float* __restrict__ Wk,
                         const float* __restrict__ Wv, bf16* __restrict__ wT,
                         float scaleq) {
  const int tid = blockIdx.x * blockDim.x + threadIdx.x;  // 0..786431
  const int n = tid >> 9, k = tid & 511;
  const float* W = (n < 512) ? Wq : ((n < 1024) ? Wk : Wv);
  const float sc = (n < 512) ? scaleq : 1.0f;
  wT[tid] = (bf16)(W[k * 512 + (n & 511)] * sc);
}

// ---------------- 512x512 transpose + convert (Wo -> Wo^T bf16) ----------------
__global__ void k_cvt_T(const float* __restrict__ w, bf16* __restrict__ wT, float scale) {
  const int tid = blockIdx.x * blockDim.x + threadIdx.x;  // 0..262143
  const int n = tid >> 9, k = tid & 511;
  wT[tid] = (bf16)(w[k * 512 + n] * scale);
}

// ---------------- V transpose + sigma permute: qkv[b][t][1024+h*32+d] -> VT'[bh][d][pi(t)] ----
// pi swaps bits 2<->3 of the kv index within each 16-block (aligns the in-register
// permlane-built PV B-frag with contiguous VT reads). kv-order-invariant math.
__global__ __launch_bounds__(256) void k_transposeV(const bf16* __restrict__ QKV,
                                                    bf16* __restrict__ VT) {
  __shared__ bf16 tile[128][36];
  const int bh = blockIdx.y, chunk = blockIdx.x;
  const int b = bh >> 4, h = bh & 15;
  const int kv0 = chunk * 128;
  const int tid = threadIdx.x;
  const int r = tid >> 1, c0 = (tid & 1) * 16;
  const size_t ib = (size_t)(b * T_ + kv0 + r) * QKVS + 1024 + h * 32 + c0;
  *(bf16x8*)&tile[r][c0]     = *(const bf16x8*)&QKV[ib];
  *(bf16x8*)&tile[r][c0 + 8] = *(const bf16x8*)&QKV[ib + 8];
  __syncthreads();
  const int d = tid >> 3, j0 = (tid & 7) * 16;
  bf16x8 o0, o1;
#pragma unroll
  for (int i = 0; i < 4; ++i) {
    o0[i]     = tile[j0 + i][d];       // pos 0..3   <- kv 0..3
    o0[i + 4] = tile[j0 + 8 + i][d];   // pos 4..7   <- kv 8..11
    o1[i]     = tile[j0 + 4 + i][d];   // pos 8..11  <- kv 4..7
    o1[i + 4] = tile[j0 + 12 + i][d];  // pos 12..15 <- kv 12..15
  }
  const size_t ob = ((size_t)bh * 32 + d) * T_ + kv0 + j0;
  *(bf16x8*)&VT[ob] = o0;
  *(bf16x8*)&VT[ob + 8] = o1;
}

// ---------------- bf16 GEMM: C[M x N] = A[M x 512] * B, B given as BT[N x 512] ----------------
// cstride = C row stride (1536 for fused QKV, 512 for the output projection).
template <int OUTF32>
__global__ __launch_bounds__(256) void k_gemm(const bf16* __restrict__ A,
                                              const bf16* __restrict__ BT,
                                              void* __restrict__ Cout,
                                              const float* __restrict__ bias,
                                              int cstride) {
  __shared__ bf16 As[128][40];
  __shared__ bf16 Bs[128][40];
  const int bn = blockIdx.x * 128;
  const int bm = blockIdx.y * 128;
  const int tid = threadIdx.x;
  const int l = tid & 63, wid = tid >> 6;
  const int ln = l & 15, ku = l >> 4;
  const int wm = (wid >> 1) * 64, wn = (wid & 1) * 64;
  const int sr = tid >> 2, sc = (tid & 3) * 8;

  f32x4 acc[4][4] = {};

  for (int ks = 0; ks < 512; ks += 32) {
    __syncthreads();
    *(bf16x8*)&As[sr][sc]      = *(const bf16x8*)&A[(size_t)(bm + sr) * 512 + ks + sc];
    *(bf16x8*)&As[sr + 64][sc] = *(const bf16x8*)&A[(size_t)(bm + sr + 64) * 512 + ks + sc];
    *(bf16x8*)&Bs[sr][sc]      = *(const bf16x8*)&BT[(size_t)(bn + sr) * 512 + ks + sc];
    *(bf16x8*)&Bs[sr + 64][sc] = *(const bf16x8*)&BT[(size_t)(bn + sr + 64) * 512 + ks + sc];
    __syncthreads();

    bf16x8 af[4], bfr[4];
#pragma unroll
    for (int mt = 0; mt < 4; ++mt) af[mt] = *(const bf16x8*)&As[wm + mt * 16 + ln][ku * 8];
#pragma unroll
    for (int nt = 0; nt < 4; ++nt) bfr[nt] = *(const bf16x8*)&Bs[wn + nt * 16 + ln][ku * 8];
#pragma unroll
    for (int mt = 0; mt < 4; ++mt)
#pragma unroll
      for (int nt = 0; nt < 4; ++nt)
        acc[mt][nt] = __builtin_amdgcn_mfma_f32_16x16x32_bf16(af[mt], bfr[nt], acc[mt][nt], 0, 0, 0);
  }

#pragma unroll
  for (int mt = 0; mt < 4; ++mt)
#pragma unroll
    for (int nt = 0; nt < 4; ++nt)
#pragma unroll
      for (int r = 0; r < 4; ++r) {
        const int row = bm + wm + mt * 16 + ku * 4 + r;
        const int col = bn + wn + nt * 16 + ln;
        const float v = acc[mt][nt][r];
        if (OUTF32)
          ((float*)Cout)[(size_t)row * cstride + col] = v + bias[col];
        else
          ((bf16*)Cout)[(size_t)row * cstride + col] = (bf16)v;
      }
}

// ---------------- flash attention: R13 sync (best measured) + T5 setprio ----------------
// grid (qt=64, bh=64), 256 threads = 4 waves, 32 q-rows/wave. Q/K read from the fused
// qkv buffer (row stride 1536; K at column offset 512). Two kv-blocks per barrier
// (R13: best of the three sync structures tried; R14's counted-vmcnt ring was neutral).
// s_setprio(1) wraps the MFMA clusters (T5: attn-positive per phase-diverse blocks).
// All verified machinery unchanged: both-sides XOR swizzle (conflicts = 0), sigma-VT',
// in-register P via permlane32_swap, Z-via-ones-MFMA, fixed-shift exp2 softmax.
__global__ __launch_bounds__(256, 5) void k_attn(const bf16* __restrict__ QKV,
                                                 const bf16* __restrict__ VT,
                                                 bf16* __restrict__ O) {
  __shared__ bf16 ks[2][2][64][32];   // [buf][sub][kv][d]   8 KB/buf
  __shared__ bf16 vts[2][2][32][64];  // [buf][sub][d][kv']  8 KB/buf
  const int qt = blockIdx.x;
  const int bh = blockIdx.y;
  const int b = bh >> 4, h = bh & 15;
  const size_t baseq = (size_t)b * T_ * QKVS + h * 32;   // Q columns
  const size_t baseo = (size_t)b * T_ * 512 + h * 32;    // O columns
  const size_t vtbase = (size_t)bh * 32 * T_;
  const int tid = threadIdx.x;
  const int l = tid & 63, w = tid >> 6;
  const int ln = l & 15, ku = l >> 4;

  // two Q B-frags: q = q0 + j*16 + ln
  const int q0 = qt * 128 + w * 32;
  bf16x8 qf[2];
#pragma unroll
  for (int j = 0; j < 2; ++j)
    qf[j] = *(const bf16x8*)&QKV[baseq + (size_t)(q0 + j * 16 + ln) * QKVS + ku * 8];

  // ones A-frag for Z-MFMA (bf16 1.0 everywhere)
  const u32 one2 = 0x3F803F80u;
  u32x4 onesu = {one2, one2, one2, one2};
  const bf16x8 ones = __builtin_bit_cast(bf16x8, onesu);

  // ---- staging source pointers (pre-swizzled global columns) ----
  const int krow = tid >> 2;
  const int kchS = ((tid & 3) ^ ((krow >> 1) & 3)) * 8;
  const int vrow = tid >> 3;
  const int vchS = ((tid & 7) ^ (vrow & 7)) * 8;
  const bf16* gk = QKV + baseq + 512 + (size_t)krow * QKVS + kchS;  // K columns
  const bf16* gv = VT + vtbase + (size_t)vrow * T_ + vchS;
  const int KSUB = 64 * QKVS;  // one kv-block of K rows

  // per-wave LDS DMA destinations (lane i writes dst + i*16 B); sub 1 at +2048 elems
  bf16* dk0 = &ks[0][0][w * 16][0];
  bf16* dk1 = &ks[1][0][w * 16][0];
  bf16* dv0 = &vts[0][0][w * 8][0];
  bf16* dv1 = &vts[1][0][w * 8][0];

  // ---- loop-invariant swizzled read addresses (CUR*8192 + sub*4096 added in body) ----
  // K-frag:  row = t*16+ln, byte = row*64 + 16*(ku ^ ((ln>>1)&3))
  const char* ksr = (const char*)&ks[0][0][0][0] + ln * 64 + 16 * (ku ^ ((ln >> 1) & 3));
  // VT-frag: row = hh*16+ln, byte = row*128 + 16*((c*4+ku) ^ (ln&7))
  const char* vr0 = (const char*)&vts[0][0][0][0] + ln * 128 + 16 * ((ku) ^ (ln & 7));
  const char* vr1 = (const char*)&vts[0][0][0][0] + ln * 128 + 16 * ((4 + ku) ^ (ln & 7));

  f32x4 o[2][2] = {};
  f32x4 zacc[2] = {};

  // prologue: DMA-stage kv-blocks 0,1 into buffer 0
  __builtin_amdgcn_global_load_lds(GLBP(gk), LDSP(dk0), 16, 0, 0);
  __builtin_amdgcn_global_load_lds(GLBP(gk + KSUB), LDSP(dk0 + 2048), 16, 0, 0);
  __builtin_amdgcn_global_load_lds(GLBP(gv), LDSP(dv0), 16, 0, 0);
  __builtin_amdgcn_global_load_lds(GLBP(gv + 64), LDSP(dv0 + 2048), 16, 0, 0);
  gk += 2 * KSUB;
  gv += 128;
  __syncthreads();

#define KV_BODY2(CUR, DKN, DVN)                                                         \
  {                                                                                     \
    __builtin_amdgcn_global_load_lds(GLBP(gk), LDSP(DKN), 16, 0, 0);                    \
    __builtin_amdgcn_global_load_lds(GLBP(gk + KSUB), LDSP(DKN + 2048), 16, 0, 0);      \
    __builtin_amdgcn_global_load_lds(GLBP(gv), LDSP(DVN), 16, 0, 0);                    \
    __builtin_amdgcn_global_load_lds(GLBP(gv + 64), LDSP(DVN + 2048), 16, 0, 0);        \
    gk += 2 * KSUB;                                                                     \
    gv += 128;                                                                          \
    _Pragma("unroll") for (int sub = 0; sub < 2; ++sub) {                               \
      _Pragma("unroll") for (int j = 0; j < 2; ++j) {                                   \
        _Pragma("unroll") for (int c = 0; c < 2; ++c) {                                 \
          const bf16x8 kf0 =                                                            \
              *(const bf16x8*)(ksr + (CUR)*8192 + sub * 4096 + c * 2048);               \
          const bf16x8 kf1 =                                                            \
              *(const bf16x8*)(ksr + (CUR)*8192 + sub * 4096 + c * 2048 + 1024);        \
          const f32x4 zz = {};                                                          \
          __builtin_amdgcn_s_setprio(1);                                                \
          f32x4 s0 = __builtin_amdgcn_mfma_f32_16x16x32_bf16(kf0, qf[j], zz, 0, 0, 0);  \
          f32x4 s1 = __builtin_amdgcn_mfma_f32_16x16x32_bf16(kf1, qf[j], zz, 0, 0, 0);  \
          __builtin_amdgcn_s_setprio(0);                                                \
          u32 lo0 = pkbf16(EXP2(s0[0]), EXP2(s0[1]));                                   \
          u32 hi0 = pkbf16(EXP2(s0[2]), EXP2(s0[3]));                                   \
          u32 lo1 = pkbf16(EXP2(s1[0]), EXP2(s1[1]));                                   \
          u32 hi1 = pkbf16(EXP2(s1[2]), EXP2(s1[3]));                                   \
          swap32(lo0, lo1);                                                             \
          swap32(hi0, hi1);                                                             \
          u32x4 pd = {lo0, hi0, lo1, hi1};                                              \
          const bf16x8 pf = __builtin_bit_cast(bf16x8, pd);                             \
          const bf16x8 va0 =                                                            \
              *(const bf16x8*)((c ? vr1 : vr0) + (CUR)*8192 + sub * 4096);              \
          const bf16x8 va1 =                                                            \
              *(const bf16x8*)((c ? vr1 : vr0) + (CUR)*8192 + sub * 4096 + 2048);       \
          __builtin_amdgcn_s_setprio(1);                                                \
          o[j][0] = __builtin_amdgcn_mfma_f32_16x16x32_bf16(va0, pf, o[j][0], 0, 0, 0); \
          o[j][1] = __builtin_amdgcn_mfma_f32_16x16x32_bf16(va1, pf, o[j][1], 0, 0, 0); \
          zacc[j] =                                                                     \
              __builtin_amdgcn_mfma_f32_16x16x32_bf16(ones, pf, zacc[j], 0, 0, 0);      \
          __builtin_amdgcn_s_setprio(0);                                                \
        }                                                                               \
      }                                                                                 \
    }                                                                                   \
    __syncthreads();                                                                    \
  }

  for (int kb = 0; kb < 128; kb += 4) {
    KV_BODY2(0, dk1, dv1);
    KV_BODY2(1, dk0, dv0);
  }
#undef KV_BODY2

  // epilogue: zacc rows are identical = full Z(q=ln); no cross-lane reduction needed
#pragma unroll
  for (int j = 0; j < 2; ++j) {
    const float iz = 1.0f / (zacc[j][0] + 1e-9f);
    bf16x4 w0, w1;
#pragma unroll
    for (int r = 0; r < 4; ++r) {
      w0[r] = (bf16)(o[j][0][r] * iz);
      w1[r] = (bf16)(o[j][1][r] * iz);
    }
    const size_t row = baseo + (size_t)(q0 + j * 16 + ln) * 512;
    *(bf16x4*)&O[row + ku * 4] = w0;
    *(bf16x4*)&O[row + 16 + ku * 4] = w1;
  }
}

extern "C" void kernel_launch(void* const* d_in, const int* in_sizes, int n_in,
                              void* d_out, int out_size, void* d_ws, size_t ws_size,
                              hipStream_t stream) {
  const float* x = (const float*)d_in[0];
  const float* Wq = (const float*)d_in[1];
  const float* Wk = (const float*)d_in[2];
  const float* Wv = (const float*)d_in[3];
  const float* Wo = (const float*)d_in[4];
  const float* bo = (const float*)d_in[5];
  float* out = (float*)d_out;

  char* ws = (char*)d_ws;
  const size_t SZ = (size_t)M_ * 512 * sizeof(bf16);  // 32 MiB
  bf16* xb = (bf16*)(ws);                             // 32 MB
  bf16* qkv = (bf16*)(ws + SZ);                       // 96 MB (M x 1536)
  bf16* ob = (bf16*)(ws + 4 * SZ);                    // 32 MB
  bf16* wqkvT = (bf16*)(ws + 5 * SZ);                 // 1.5 MB (1536 x 512)
  bf16* woT = wqkvT + 1536 * 512;                     // 0.5 MB
  bf16* vt = xb;  // reuse xb slot: xb dead after the fused QKV GEMM

  const float SCALE_L2E = 0.17677669529663687f * 1.4426950408889634f;  // (1/sqrt(32))*log2(e)

  // 1) converts (Wq pre-scaled so QK^T lands in exp2 domain)
  k_cvt<<<2048, 256, 0, stream>>>(x, xb, M_ * 512 / 4);
  k_cvt_T3<<<3072, 256, 0, stream>>>(Wq, Wk, Wv, wqkvT, SCALE_L2E);
  k_cvt_T<<<1024, 256, 0, stream>>>(Wo, woT, 1.0f);

  // 2) fused QKV projection: qkv[M][1536]
  dim3 gq(12, 256);
  k_gemm<0><<<gq, 256, 0, stream>>>(xb, wqkvT, qkv, nullptr, QKVS);

  // 3) V transpose + sigma permute (into xb slot), then flash attention
  dim3 gt(64, 64);
  k_transposeV<<<gt, 256, 0, stream>>>(qkv, vt);
  dim3 ga(64, 64);
  k_attn<<<ga, 256, 0, stream>>>(qkv, vt, ob);

  // 4) output projection (f32 + bias)
  dim3 gg(4, 256);
  k_gemm<1><<<gg, 256, 0, stream>>>(ob, woT, out, bo, 512);
}

// Round 16
// 788.622 us; speedup vs baseline: 1.0560x; 1.0560x over previous
//
#include <hip/hip_runtime.h>
#include <hip/hip_bf16.h>
#include <math.h>

typedef __bf16 bf16;
typedef __bf16 bf16x2 __attribute__((ext_vector_type(2)));
typedef __bf16 bf16x4 __attribute__((ext_vector_type(4)));
typedef __bf16 bf16x8 __attribute__((ext_vector_type(8)));
typedef float f32x4 __attribute__((ext_vector_type(4)));
typedef unsigned int u32;
typedef u32 u32x4 __attribute__((ext_vector_type(4)));

#define B_ 4
#define T_ 8192
#define D_ 512
#define H_ 16
#define HD_ 32
#define M_ (B_ * T_)  // 32768 rows

#if __has_builtin(__builtin_amdgcn_exp2f)
#define EXP2(x) __builtin_amdgcn_exp2f(x)
#else
#define EXP2(x) exp2f(x)
#endif

// address-space casts for global_load_lds
#define LDSP(p) ((__attribute__((address_space(3))) void*)(p))
#define GLBP(p) ((const __attribute__((address_space(1))) void*)(p))

// pack two f32 -> dword of 2 bf16
static __device__ __forceinline__ u32 pkbf16(float a, float b) {
  bf16x2 t;
  t[0] = (bf16)a;
  t[1] = (bf16)b;
  return __builtin_bit_cast(u32, t);
}

// v_permlane32_swap_b32: a' = [a.lo32, b.lo32], b' = [a.hi32, b.hi32]
static __device__ __forceinline__ void swap32(u32& a, u32& b) {
#if __has_builtin(__builtin_amdgcn_permlane32_swap)
  auto r = __builtin_amdgcn_permlane32_swap(a, b, false, false);
  a = r[0];
  b = r[1];
#else
  asm volatile("v_permlane32_swap_b32 %0, %1" : "+v"(a), "+v"(b));
#endif
}

// ---------------- fp32 -> bf16 convert (vectorized, grid-stride) ----------------
__global__ void k_cvt(const float* __restrict__ in, bf16* __restrict__ out, int n4) {
  int i = blockIdx.x * blockDim.x + threadIdx.x;
  const int stride = gridDim.x * blockDim.x;
  for (; i < n4; i += stride) {
    const float4 v = ((const float4*)in)[i];
    bf16x4 o;
    o.x = (bf16)v.x; o.y = (bf16)v.y; o.z = (bf16)v.z; o.w = (bf16)v.w;
    ((bf16x4*)out)[i] = o;
  }
}

// ---------------- fused Wq/Wk/Wv transpose+convert -> wqkvT[1536][512] ----------------
// rows 0-511 = Wq^T (pre-scaled by scale*log2e), 512-1023 = Wk^T, 1024-1535 = Wv^T.
__global__ void k_cvt_T3(const float* __restrict__ Wq, const float* __restrict__ Wk,
                         const float* __restrict__ Wv, bf16* __restrict__ wT,
                         float scaleq) {
  const int tid = blockIdx.x * blockDim.x + threadIdx.x;  // 0..786431
  const int n = tid >> 9, k = tid & 511;
  const float* W = (n < 512) ? Wq : ((n < 1024) ? Wk : Wv);
  const float sc = (n < 512) ? scaleq : 1.0f;
  wT[tid] = (bf16)(W[k * 512 + (n & 511)] * sc);
}

// ---------------- 512x512 transpose + convert (Wo -> Wo^T bf16) ----------------
__global__ void k_cvt_T(const float* __restrict__ w, bf16* __restrict__ wT, float scale) {
  const int tid = blockIdx.x * blockDim.x + threadIdx.x;  // 0..262143
  const int n = tid >> 9, k = tid & 511;
  wT[tid] = (bf16)(w[k * 512 + n] * scale);
}

// ---------------- V transpose + sigma permute: V[b][t][h*32+d] -> VT'[bh][d][pi(t)] ----------
// pi swaps bits 2<->3 of the kv index within each 16-block (aligns the in-register
// permlane-built PV B-frag with contiguous VT reads). kv-order-invariant math.
__global__ __launch_bounds__(256) void k_transposeV(const bf16* __restrict__ V,
                                                    bf16* __restrict__ VT) {
  __shared__ bf16 tile[128][36];
  const int bh = blockIdx.y, chunk = blockIdx.x;
  const int b = bh >> 4, h = bh & 15;
  const int kv0 = chunk * 128;
  const int tid = threadIdx.x;
  const int r = tid >> 1, c0 = (tid & 1) * 16;
  const size_t ib = ((size_t)(b * T_ + kv0 + r)) * 512 + h * 32 + c0;
  *(bf16x8*)&tile[r][c0]     = *(const bf16x8*)&V[ib];
  *(bf16x8*)&tile[r][c0 + 8] = *(const bf16x8*)&V[ib + 8];
  __syncthreads();
  const int d = tid >> 3, j0 = (tid & 7) * 16;
  bf16x8 o0, o1;
#pragma unroll
  for (int i = 0; i < 4; ++i) {
    o0[i]     = tile[j0 + i][d];       // pos 0..3   <- kv 0..3
    o0[i + 4] = tile[j0 + 8 + i][d];   // pos 4..7   <- kv 8..11
    o1[i]     = tile[j0 + 4 + i][d];   // pos 8..11  <- kv 4..7
    o1[i + 4] = tile[j0 + 12 + i][d];  // pos 12..15 <- kv 12..15
  }
  const size_t ob = ((size_t)bh * 32 + d) * T_ + kv0 + j0;
  *(bf16x8*)&VT[ob] = o0;
  *(bf16x8*)&VT[ob + 8] = o1;
}

// ---------------- fused QKV GEMM: [q|k|v][M x 512] = A[M x 512] * wqkvT ----------------
// BT has 1536 rows (Wq^T, Wk^T, Wv^T stacked). blockIdx.x covers 12 n-blocks of 128;
// bn>>9 selects the DENSE output buffer (wave-uniform), bn&511 the column base.
// Single GEMM = A-tile traffic once instead of 3x; dense outputs keep attn staging
// at stride 512 (R15 showed stride-1536 staging + setprio cost attn 5.5%).
__global__ __launch_bounds__(256) void k_gemm_qkv(const bf16* __restrict__ A,
                                                  const bf16* __restrict__ BT,
                                                  bf16* __restrict__ Qo,
                                                  bf16* __restrict__ Ko,
                                                  bf16* __restrict__ Vo) {
  __shared__ bf16 As[128][40];
  __shared__ bf16 Bs[128][40];
  const int bn = blockIdx.x * 128;
  const int bm = blockIdx.y * 128;
  const int tid = threadIdx.x;
  const int l = tid & 63, wid = tid >> 6;
  const int ln = l & 15, ku = l >> 4;
  const int wm = (wid >> 1) * 64, wn = (wid & 1) * 64;
  const int sr = tid >> 2, sc = (tid & 3) * 8;

  f32x4 acc[4][4] = {};

  for (int ks = 0; ks < 512; ks += 32) {
    __syncthreads();
    *(bf16x8*)&As[sr][sc]      = *(const bf16x8*)&A[(size_t)(bm + sr) * 512 + ks + sc];
    *(bf16x8*)&As[sr + 64][sc] = *(const bf16x8*)&A[(size_t)(bm + sr + 64) * 512 + ks + sc];
    *(bf16x8*)&Bs[sr][sc]      = *(const bf16x8*)&BT[(size_t)(bn + sr) * 512 + ks + sc];
    *(bf16x8*)&Bs[sr + 64][sc] = *(const bf16x8*)&BT[(size_t)(bn + sr + 64) * 512 + ks + sc];
    __syncthreads();

    bf16x8 af[4], bfr[4];
#pragma unroll
    for (int mt = 0; mt < 4; ++mt) af[mt] = *(const bf16x8*)&As[wm + mt * 16 + ln][ku * 8];
#pragma unroll
    for (int nt = 0; nt < 4; ++nt) bfr[nt] = *(const bf16x8*)&Bs[wn + nt * 16 + ln][ku * 8];
#pragma unroll
    for (int mt = 0; mt < 4; ++mt)
#pragma unroll
      for (int nt = 0; nt < 4; ++nt)
        acc[mt][nt] = __builtin_amdgcn_mfma_f32_16x16x32_bf16(af[mt], bfr[nt], acc[mt][nt], 0, 0, 0);
  }

  const int mi = bn >> 9;  // 0=Q, 1=K, 2=V (wave-uniform)
  bf16* Cb = (mi == 0) ? Qo : ((mi == 1) ? Ko : Vo);
  const int cb = bn & 511;
#pragma unroll
  for (int mt = 0; mt < 4; ++mt)
#pragma unroll
    for (int nt = 0; nt < 4; ++nt)
#pragma unroll
      for (int r = 0; r < 4; ++r) {
        const int row = bm + wm + mt * 16 + ku * 4 + r;
        const int col = cb + wn + nt * 16 + ln;
        Cb[(size_t)row * 512 + col] = (bf16)acc[mt][nt][r];
      }
}

// ---------------- f32-out GEMM with bias (output projection) ----------------
__global__ __launch_bounds__(256) void k_gemm_out(const bf16* __restrict__ A,
                                                  const bf16* __restrict__ BT,
                                                  float* __restrict__ Cout,
                                                  const float* __restrict__ bias) {
  __shared__ bf16 As[128][40];
  __shared__ bf16 Bs[128][40];
  const int bn = blockIdx.x * 128;
  const int bm = blockIdx.y * 128;
  const int tid = threadIdx.x;
  const int l = tid & 63, wid = tid >> 6;
  const int ln = l & 15, ku = l >> 4;
  const int wm = (wid >> 1) * 64, wn = (wid & 1) * 64;
  const int sr = tid >> 2, sc = (tid & 3) * 8;

  f32x4 acc[4][4] = {};

  for (int ks = 0; ks < 512; ks += 32) {
    __syncthreads();
    *(bf16x8*)&As[sr][sc]      = *(const bf16x8*)&A[(size_t)(bm + sr) * 512 + ks + sc];
    *(bf16x8*)&As[sr + 64][sc] = *(const bf16x8*)&A[(size_t)(bm + sr + 64) * 512 + ks + sc];
    *(bf16x8*)&Bs[sr][sc]      = *(const bf16x8*)&BT[(size_t)(bn + sr) * 512 + ks + sc];
    *(bf16x8*)&Bs[sr + 64][sc] = *(const bf16x8*)&BT[(size_t)(bn + sr + 64) * 512 + ks + sc];
    __syncthreads();

    bf16x8 af[4], bfr[4];
#pragma unroll
    for (int mt = 0; mt < 4; ++mt) af[mt] = *(const bf16x8*)&As[wm + mt * 16 + ln][ku * 8];
#pragma unroll
    for (int nt = 0; nt < 4; ++nt) bfr[nt] = *(const bf16x8*)&Bs[wn + nt * 16 + ln][ku * 8];
#pragma unroll
    for (int mt = 0; mt < 4; ++mt)
#pragma unroll
      for (int nt = 0; nt < 4; ++nt)
        acc[mt][nt] = __builtin_amdgcn_mfma_f32_16x16x32_bf16(af[mt], bfr[nt], acc[mt][nt], 0, 0, 0);
  }

#pragma unroll
  for (int mt = 0; mt < 4; ++mt)
#pragma unroll
    for (int nt = 0; nt < 4; ++nt)
#pragma unroll
      for (int r = 0; r < 4; ++r) {
        const int row = bm + wm + mt * 16 + ku * 4 + r;
        const int col = bn + wn + nt * 16 + ln;
        Cout[(size_t)row * 512 + col] = acc[mt][nt][r] + bias[col];
      }
}

// ---------------- flash attention: R13 structure verbatim (best measured: 675 us) ----------
// grid (qt=64, bh=64), 256 threads = 4 waves, 32 q-rows/wave, dense Q/K/VT' inputs.
// Two kv-blocks per barrier; DMA staging via global_load_lds; both-sides XOR swizzle
// (conflicts measured 0); sigma-baked VT'; in-register P via permlane32_swap;
// Z-via-ones-MFMA; fixed-shift exp2 softmax. NO setprio (R15 A/B: negative here).
__global__ __launch_bounds__(256, 5) void k_attn(const bf16* __restrict__ Q,
                                                 const bf16* __restrict__ K,
                                                 const bf16* __restrict__ VT,
                                                 bf16* __restrict__ O) {
  __shared__ bf16 ks[2][2][64][32];   // [buf][sub][kv][d]   8 KB/buf
  __shared__ bf16 vts[2][2][32][64];  // [buf][sub][d][kv']  8 KB/buf
  const int qt = blockIdx.x;
  const int bh = blockIdx.y;
  const int b = bh >> 4, h = bh & 15;
  const size_t base = (size_t)b * T_ * 512 + (size_t)h * 32;
  const size_t vtbase = (size_t)bh * 32 * T_;
  const int tid = threadIdx.x;
  const int l = tid & 63, w = tid >> 6;
  const int ln = l & 15, ku = l >> 4;

  // two Q B-frags: q = q0 + j*16 + ln
  const int q0 = qt * 128 + w * 32;
  bf16x8 qf[2];
#pragma unroll
  for (int j = 0; j < 2; ++j)
    qf[j] = *(const bf16x8*)&Q[base + (size_t)(q0 + j * 16 + ln) * 512 + ku * 8];

  // ones A-frag for Z-MFMA (bf16 1.0 everywhere)
  const u32 one2 = 0x3F803F80u;
  u32x4 onesu = {one2, one2, one2, one2};
  const bf16x8 ones = __builtin_bit_cast(bf16x8, onesu);

  // ---- staging source pointers (pre-swizzled global columns) ----
  const int krow = tid >> 2;
  const int kchS = ((tid & 3) ^ ((krow >> 1) & 3)) * 8;
  const int vrow = tid >> 3;
  const int vchS = ((tid & 7) ^ (vrow & 7)) * 8;
  const bf16* gk = K + base + (size_t)krow * 512 + kchS;
  const bf16* gv = VT + vtbase + (size_t)vrow * T_ + vchS;

  // per-wave LDS DMA destinations (lane i writes dst + i*16 B); sub 1 at +2048 elems
  bf16* dk0 = &ks[0][0][w * 16][0];
  bf16* dk1 = &ks[1][0][w * 16][0];
  bf16* dv0 = &vts[0][0][w * 8][0];
  bf16* dv1 = &vts[1][0][w * 8][0];

  // ---- loop-invariant swizzled read addresses (CUR*8192 + sub*4096 added in body) ----
  // K-frag:  row = t*16+ln, byte = row*64 + 16*(ku ^ ((ln>>1)&3))
  const char* ksr = (const char*)&ks[0][0][0][0] + ln * 64 + 16 * (ku ^ ((ln >> 1) & 3));
  // VT-frag: row = hh*16+ln, byte = row*128 + 16*((c*4+ku) ^ (ln&7))
  const char* vr0 = (const char*)&vts[0][0][0][0] + ln * 128 + 16 * ((ku) ^ (ln & 7));
  const char* vr1 = (const char*)&vts[0][0][0][0] + ln * 128 + 16 * ((4 + ku) ^ (ln & 7));

  f32x4 o[2][2] = {};
  f32x4 zacc[2] = {};

  // prologue: DMA-stage kv-blocks 0,1 into buffer 0
  __builtin_amdgcn_global_load_lds(GLBP(gk), LDSP(dk0), 16, 0, 0);
  __builtin_amdgcn_global_load_lds(GLBP(gk + 32768), LDSP(dk0 + 2048), 16, 0, 0);
  __builtin_amdgcn_global_load_lds(GLBP(gv), LDSP(dv0), 16, 0, 0);
  __builtin_amdgcn_global_load_lds(GLBP(gv + 64), LDSP(dv0 + 2048), 16, 0, 0);
  gk += 2 * 64 * 512;
  gv += 128;
  __syncthreads();

#define KV_BODY2(CUR, DKN, DVN)                                                         \
  {                                                                                     \
    __builtin_amdgcn_global_load_lds(GLBP(gk), LDSP(DKN), 16, 0, 0);                    \
    __builtin_amdgcn_global_load_lds(GLBP(gk + 32768), LDSP(DKN + 2048), 16, 0, 0);     \
    __builtin_amdgcn_global_load_lds(GLBP(gv), LDSP(DVN), 16, 0, 0);                    \
    __builtin_amdgcn_global_load_lds(GLBP(gv + 64), LDSP(DVN + 2048), 16, 0, 0);        \
    gk += 2 * 64 * 512;                                                                 \
    gv += 128;                                                                          \
    _Pragma("unroll") for (int sub = 0; sub < 2; ++sub) {                               \
      _Pragma("unroll") for (int j = 0; j < 2; ++j) {                                   \
        _Pragma("unroll") for (int c = 0; c < 2; ++c) {                                 \
          const bf16x8 kf0 =                                                            \
              *(const bf16x8*)(ksr + (CUR)*8192 + sub * 4096 + c * 2048);               \
          const bf16x8 kf1 =                                                            \
              *(const bf16x8*)(ksr + (CUR)*8192 + sub * 4096 + c * 2048 + 1024);        \
          const f32x4 zz = {};                                                          \
          f32x4 s0 = __builtin_amdgcn_mfma_f32_16x16x32_bf16(kf0, qf[j], zz, 0, 0, 0);  \
          f32x4 s1 = __builtin_amdgcn_mfma_f32_16x16x32_bf16(kf1, qf[j], zz, 0, 0, 0);  \
          u32 lo0 = pkbf16(EXP2(s0[0]), EXP2(s0[1]));                                   \
          u32 hi0 = pkbf16(EXP2(s0[2]), EXP2(s0[3]));                                   \
          u32 lo1 = pkbf16(EXP2(s1[0]), EXP2(s1[1]));                                   \
          u32 hi1 = pkbf16(EXP2(s1[2]), EXP2(s1[3]));                                   \
          swap32(lo0, lo1);                                                             \
          swap32(hi0, hi1);                                                             \
          u32x4 pd = {lo0, hi0, lo1, hi1};                                              \
          const bf16x8 pf = __builtin_bit_cast(bf16x8, pd);                             \
          const bf16x8 va0 =                                                            \
              *(const bf16x8*)((c ? vr1 : vr0) + (CUR)*8192 + sub * 4096);              \
          const bf16x8 va1 =                                                            \
              *(const bf16x8*)((c ? vr1 : vr0) + (CUR)*8192 + sub * 4096 + 2048);       \
          o[j][0] = __builtin_amdgcn_mfma_f32_16x16x32_bf16(va0, pf, o[j][0], 0, 0, 0); \
          o[j][1] = __builtin_amdgcn_mfma_f32_16x16x32_bf16(va1, pf, o[j][1], 0, 0, 0); \
          zacc[j] =                                                                     \
              __builtin_amdgcn_mfma_f32_16x16x32_bf16(ones, pf, zacc[j], 0, 0, 0);      \
        }                                                                               \
      }                                                                                 \
    }                                                                                   \
    __syncthreads();                                                                    \
  }

  for (int kb = 0; kb < 128; kb += 4) {
    KV_BODY2(0, dk1, dv1);
    KV_BODY2(1, dk0, dv0);
  }
#undef KV_BODY2

  // epilogue: zacc rows are identical = full Z(q=ln); no cross-lane reduction needed
#pragma unroll
  for (int j = 0; j < 2; ++j) {
    const float iz = 1.0f / (zacc[j][0] + 1e-9f);
    bf16x4 w0, w1;
#pragma unroll
    for (int r = 0; r < 4; ++r) {
      w0[r] = (bf16)(o[j][0][r] * iz);
      w1[r] = (bf16)(o[j][1][r] * iz);
    }
    const size_t row = base + (size_t)(q0 + j * 16 + ln) * 512;
    *(bf16x4*)&O[row + ku * 4] = w0;
    *(bf16x4*)&O[row + 16 + ku * 4] = w1;
  }
}

extern "C" void kernel_launch(void* const* d_in, const int* in_sizes, int n_in,
                              void* d_out, int out_size, void* d_ws, size_t ws_size,
                              hipStream_t stream) {
  const float* x = (const float*)d_in[0];
  const float* Wq = (const float*)d_in[1];
  const float* Wk = (const float*)d_in[2];
  const float* Wv = (const float*)d_in[3];
  const float* Wo = (const float*)d_in[4];
  const float* bo = (const float*)d_in[5];
  float* out = (float*)d_out;

  char* ws = (char*)d_ws;
  const size_t SZ = (size_t)M_ * 512 * sizeof(bf16);  // 32 MiB
  bf16* xb = (bf16*)(ws);
  bf16* qb = (bf16*)(ws + SZ);
  bf16* kb = (bf16*)(ws + 2 * SZ);
  bf16* vb = (bf16*)(ws + 3 * SZ);
  bf16* ob = (bf16*)(ws + 4 * SZ);
  bf16* wqkvT = (bf16*)(ws + 5 * SZ);   // 1.5 MB (1536 x 512)
  bf16* woT = wqkvT + 1536 * 512;       // 0.5 MB
  bf16* vt = xb;  // reuse xb slot: xb dead after the fused QKV GEMM

  const float SCALE_L2E = 0.17677669529663687f * 1.4426950408889634f;  // (1/sqrt(32))*log2(e)

  // 1) converts (Wq pre-scaled so QK^T lands in exp2 domain)
  k_cvt<<<2048, 256, 0, stream>>>(x, xb, M_ * 512 / 4);
  k_cvt_T3<<<3072, 256, 0, stream>>>(Wq, Wk, Wv, wqkvT, SCALE_L2E);
  k_cvt_T<<<1024, 256, 0, stream>>>(Wo, woT, 1.0f);

  // 2) fused QKV projection -> dense qb, kb, vb (stride 512 each)
  dim3 gq(12, 256);
  k_gemm_qkv<<<gq, 256, 0, stream>>>(xb, wqkvT, qb, kb, vb);

  // 3) V transpose + sigma permute (into xb slot), then flash attention
  dim3 gt(64, 64);
  k_transposeV<<<gt, 64 * 4, 0, stream>>>(vb, vt);
  dim3 ga(64, 64);
  k_attn<<<ga, 256, 0, stream>>>(qb, kb, vt, ob);

  // 4) output projection (f32 + bias)
  dim3 gg(4, 256);
  k_gemm_out<<<gg, 256, 0, stream>>>(ob, woT, out, bo);
}